// Round 7
// baseline (361.129 us; speedup 1.0000x reference)
//
#include <hip/hip_runtime.h>
#include <hip/hip_bf16.h>

// SGNHeadLSS — round 13: async global_load_lds prefetch + persistent blocks.
// r12 post-mortem: 2-chain ILP null (93.8us), traffic clean. Series (r8
// 83.4 staged / r9 88 direct / r12 94 wide) => per-block serial chain
// ~12.5k cy x 16 blocks/CU with ZERO inter-block overlap (convoyed HBM
// bursts; VALUBusy ~20%). Fix (the one untried mechanism):
//  - TILES=8 per block, grid 512 = exactly 2 blocks/CU (persistent);
//    cold x3d load paid 2x/CU not 16x.
//  - next tile's x3d prefetched via __builtin_amdgcn_global_load_lds
//    (async, ZERO VGPR -> no r10/r11 spill) into a 32KB f32 LDS stage
//    during current tile's compute; drained by the barrier's implicit
//    vmcnt(0). HBM demand becomes continuous.
//  - pack = LDS->LDS: 8x ds_read_b128 + 4x ds_write_b128 per thread
//    (16-way-conflict b32 writes of r8/r12 -> 4x fewer write insts).
//  - AUX merged into GEMM1 (reads feats pre-select, shares A-frags):
//    5 -> 4 serial MFMA phases.
// Compute math identical to r9/r12 (passed, absmax 0.017-0.024).

#define NVOX 262144
#define NU   65536
#define NM   196608
#define CIN  128
#define CHALF 64
#define NCLS 20
#define TR   64
#define TILES 8
#define NBLK (NVOX / (TR * TILES))  // 512

#define SXS 136   // sX row stride in u16 (272B, 16B-aligned)
#define SHS 72    // sH row stride in u16 (144B, 16B-aligned)
#define SOS 21    // sOut row stride in f32 (bank-conflict-free readback)

// ws layout (u16 units), fragment order: [nt][kc][lane]*8
#define W1F  0       // nt4 kc4  -> 8192
#define W2F  8192    // nt8 kc2  -> 8192
#define SDBF 16384   // nt4 kc4  -> 8192
#define SSCF 24576   // nt2 kc2  -> 2048
#define AUXF 26624   // nt2 kc4  -> 4096
#define WS_WT 30720  // 61440 bytes of weights; rank[NVOX] int32 follows

typedef unsigned short u16;
typedef short    bf16x8 __attribute__((ext_vector_type(8)));
typedef float    f32x4  __attribute__((ext_vector_type(4)));

__device__ __forceinline__ u16 f2b(float f) {
    __hip_bfloat16 h = __float2bfloat16(f);
    return *(u16*)&h;
}

// B-frag layout: lane=q*16+n15 holds B[k=kc*32+q*8+j][n=nt*16+n15], j=0..7
__global__ void prep_weights(const float* __restrict__ w1,  const float* __restrict__ w2,
                             const float* __restrict__ sdbw,const float* __restrict__ sscw,
                             const float* __restrict__ auxw,
                             const int* __restrict__ uidx,  const int* __restrict__ midx,
                             u16* __restrict__ ws) {
    int i = blockIdx.x * blockDim.x + threadIdx.x;
    const int stride = gridDim.x * blockDim.x;
    int* __restrict__ rank = (int*)(ws + WS_WT);
    for (int t = i; t < NU; t += stride) rank[uidx[t]] = t;
    for (int t = i; t < NM; t += stride) rank[midx[t]] = -1;
    for (; i < WS_WT; i += stride) {
        float v;
        if (i < W2F) {                      // w1^frag: N=64, K=128
            int t = i, j = t & 7, lane = (t >> 3) & 63, kc = (t >> 9) & 3, nt = t >> 11;
            int k = kc*32 + (lane >> 4)*8 + j, n = nt*16 + (lane & 15);
            v = w1[k*CHALF + n];
        } else if (i < SDBF) {              // w2^frag: N=128, K=64
            int t = i - W2F, j = t & 7, lane = (t >> 3) & 63, kc = (t >> 9) & 1, nt = t >> 10;
            int k = kc*32 + (lane >> 4)*8 + j, n = nt*16 + (lane & 15);
            v = w2[k*CIN + n];
        } else if (i < SSCF) {              // sdb^frag: N=64, K=128
            int t = i - SDBF, j = t & 7, lane = (t >> 3) & 63, kc = (t >> 9) & 3, nt = t >> 11;
            int k = kc*32 + (lane >> 4)*8 + j, n = nt*16 + (lane & 15);
            v = sdbw[k*CHALF + n];
        } else if (i < AUXF) {              // ssc^frag: N=32(pad), K=64
            int t = i - SSCF, j = t & 7, lane = (t >> 3) & 63, kc = (t >> 9) & 1, nt = t >> 10;
            int k = kc*32 + (lane >> 4)*8 + j, n = nt*16 + (lane & 15);
            v = (n < NCLS) ? sscw[k*NCLS + n] : 0.f;
        } else {                            // aux^frag: N=32(pad), K=128
            int t = i - AUXF, j = t & 7, lane = (t >> 3) & 63, kc = (t >> 9) & 3, nt = t >> 11;
            int k = kc*32 + (lane >> 4)*8 + j, n = nt*16 + (lane & 15);
            v = (n < NCLS) ? auxw[k*NCLS + n] : 0.f;
        }
        ws[i] = f2b(v);
    }
}

__global__ __launch_bounds__(256, 2)
void sgn_mfma(const float* __restrict__ x3d,
              const float* __restrict__ b1,   const float* __restrict__ lng,
              const float* __restrict__ lnb,  const float* __restrict__ bb2,
              const float* __restrict__ sdbb, const float* __restrict__ sscb,
              const float* __restrict__ auxb,
              const int* __restrict__ rank,   const u16* __restrict__ wt,
              float* __restrict__ out)
{
    __shared__ __align__(16) float sStage[CIN * TR];   // [ch][vox] f32, 32KB
    __shared__ __align__(16) u16 sX[TR * SXS];         // feats/vox bf16 [r][k]
    __shared__ __align__(16) u16 sH[TR * SHS];         // h / d          [r][k]
    __shared__ __align__(16) float sOut[TR * SOS];     // ssc logits     [r][ch]
    __shared__ int sRank[2 * TR];

    const int tid  = threadIdx.x;
    const int base = (int)blockIdx.x * (TR * TILES);
    const int w    = tid >> 6;       // wave 0..3
    const int l    = tid & 63;

    // ---- async stage: tile at voxel base pv -> sStage (zero VGPR) ----
    // wave w covers channels [w*32, w*32+32); inst k moves 4 ch-rows (1KB).
    // LDS dest is wave-uniform base; HW lands lane at base + lane*16,
    // i.e. [chbase + (l>>4)][(l&15)*4] — gsrc matches that slot.
    auto STAGE = [&](int pv) {
        const float* gs = x3d + (size_t)(w*32 + (l >> 4)) * NVOX + pv + (l & 15)*4;
        #pragma unroll
        for (int k = 0; k < 8; ++k)
            __builtin_amdgcn_global_load_lds(gs + (size_t)(k*4) * NVOX,
                                             &sStage[(w*32 + k*4) * TR],
                                             16, 0, 0);
    };

    // ---- pack: sStage f32 [ch][vox] -> sX bf16 [vox][ch] ----
    // thread: 8 channels (gch..gch+7) x 4 vox; 8 ds_read_b128 + 4 ds_write_b128
    auto PACK = [&]() {
        const int gch = (tid >> 4) * 8;
        const int vp  = (tid & 15) * 4;
        f32x4 cv[8];
        #pragma unroll
        for (int r = 0; r < 8; ++r)
            cv[r] = *(const f32x4*)&sStage[(gch + r) * TR + vp];
        #pragma unroll
        for (int j = 0; j < 4; ++j) {
            bf16x8 row;
            #pragma unroll
            for (int r = 0; r < 8; ++r) ((u16*)&row)[r] = f2b(cv[r][j]);
            *(bf16x8*)&sX[(vp + j) * SXS + gch] = row;
        }
    };

    // ---- prologue: tile 0 ----
    STAGE(base);
    if (tid < TR) sRank[tid] = rank[base + tid];
    __syncthreads();     // implicit vmcnt(0): stage landed
    PACK();
    __syncthreads();     // sX + sRank ready

    const int m0   = w * 16;          // wave's 16-row slice
    const int lane = l;
    const int q    = lane >> 4;
    const int n15  = lane & 15;
    const int kq   = q * 8;

    #pragma unroll 1
    for (int t = 0; t < TILES; ++t) {
        const int p0 = base + t * TR;
        const int cb = t & 1, nb = cb ^ 1;
        int rkn = 0;

        // ---- issue next tile's async stage + rank (hidden under compute) ----
        if (t + 1 < TILES) {
            STAGE(p0 + TR);
            if (tid < TR) rkn = rank[p0 + TR + tid];
        }

        // ---- GEMM1+AUX merged: feats @ w1 (->LN->sH) and feats @ aux_w ----
        {
            f32x4 acc[4], acca[2];
            #pragma unroll
            for (int nt = 0; nt < 4; ++nt) {
                const float b = b1[nt*16 + n15];
                acc[nt] = (f32x4){b, b, b, b};
            }
            #pragma unroll
            for (int nt = 0; nt < 2; ++nt) {
                const int col = nt*16 + n15;
                const float b = (col < NCLS) ? auxb[col] : 0.f;
                acca[nt] = (f32x4){b, b, b, b};
            }
            #pragma unroll
            for (int kc = 0; kc < 4; ++kc) {
                const bf16x8 a = *(const bf16x8*)&sX[(m0 + n15) * SXS + kc*32 + kq];
                #pragma unroll
                for (int nt = 0; nt < 4; ++nt) {
                    const bf16x8 b = *(const bf16x8*)&wt[W1F + ((nt*4 + kc)*64 + lane)*8];
                    acc[nt] = __builtin_amdgcn_mfma_f32_16x16x32_bf16(a, b, acc[nt], 0, 0, 0);
                }
                #pragma unroll
                for (int nt = 0; nt < 2; ++nt) {
                    const bf16x8 b = *(const bf16x8*)&wt[AUXF + ((nt*4 + kc)*64 + lane)*8];
                    acca[nt] = __builtin_amdgcn_mfma_f32_16x16x32_bf16(a, b, acca[nt], 0, 0, 0);
                }
            }
            // aux store now (frees acca; predicated on unmasked)
            {
                const size_t abase = (size_t)NCLS * NVOX;
                #pragma unroll
                for (int reg = 0; reg < 4; ++reg) {
                    const int rk = sRank[cb*TR + m0 + q*4 + reg];
                    if (rk >= 0) {
                        out[abase + (size_t)rk * NCLS + n15] = acca[0][reg];
                        if (n15 < 4)
                            out[abase + (size_t)rk * NCLS + 16 + n15] = acca[1][reg];
                    }
                }
            }
            // LN -> leaky -> sH
            float gv[4], ev[4];
            #pragma unroll
            for (int nt = 0; nt < 4; ++nt) { gv[nt] = lng[nt*16 + n15]; ev[nt] = lnb[nt*16 + n15]; }
            #pragma unroll
            for (int reg = 0; reg < 4; ++reg) {
                float s1 = acc[0][reg] + acc[1][reg] + acc[2][reg] + acc[3][reg];
                float s2 = acc[0][reg]*acc[0][reg] + acc[1][reg]*acc[1][reg]
                         + acc[2][reg]*acc[2][reg] + acc[3][reg]*acc[3][reg];
                #pragma unroll
                for (int m = 1; m <= 8; m <<= 1) {
                    s1 += __shfl_xor(s1, m, 64);
                    s2 += __shfl_xor(s2, m, 64);
                }
                const float mu  = s1 * (1.f/64.f);
                const float var = s2 * (1.f/64.f) - mu*mu;
                const float rs  = rsqrtf(var + 1e-5f);
                #pragma unroll
                for (int nt = 0; nt < 4; ++nt) {
                    float h = (acc[nt][reg] - mu) * rs * gv[nt] + ev[nt];
                    h = h > 0.f ? h : 0.01f*h;
                    sH[(m0 + q*4 + reg) * SHS + nt*16 + n15] = f2b(h);
                }
            }
        }

        // ---- GEMM2: h @ w2 -> prior; overwrite MASKED rows of sX ----
        {
            f32x4 acc2[8];
            #pragma unroll
            for (int nt = 0; nt < 8; ++nt) {
                const float b = bb2[nt*16 + n15];
                acc2[nt] = (f32x4){b, b, b, b};
            }
            #pragma unroll
            for (int kc = 0; kc < 2; ++kc) {
                const bf16x8 a = *(const bf16x8*)&sH[(m0 + n15) * SHS + kc*32 + kq];
                #pragma unroll
                for (int nt = 0; nt < 8; ++nt) {
                    const bf16x8 b = *(const bf16x8*)&wt[W2F + ((nt*2 + kc)*64 + lane)*8];
                    acc2[nt] = __builtin_amdgcn_mfma_f32_16x16x32_bf16(a, b, acc2[nt], 0, 0, 0);
                }
            }
            #pragma unroll
            for (int reg = 0; reg < 4; ++reg) {
                const int row = m0 + q*4 + reg;
                if (sRank[cb*TR + row] < 0) {   // masked -> vox = prior
                    #pragma unroll
                    for (int nt = 0; nt < 8; ++nt)
                        sX[row * SXS + nt*16 + n15] = f2b(acc2[nt][reg]);
                }                               // unmasked -> vox = feats
            }
        }

        // ---- SDB: vox @ sdb_w -> leaky -> sH (= d) ----
        {
            f32x4 accd[4];
            #pragma unroll
            for (int nt = 0; nt < 4; ++nt) {
                const float b = sdbb[nt*16 + n15];
                accd[nt] = (f32x4){b, b, b, b};
            }
            #pragma unroll
            for (int kc = 0; kc < 4; ++kc) {
                const bf16x8 a = *(const bf16x8*)&sX[(m0 + n15) * SXS + kc*32 + kq];
                #pragma unroll
                for (int nt = 0; nt < 4; ++nt) {
                    const bf16x8 b = *(const bf16x8*)&wt[SDBF + ((nt*4 + kc)*64 + lane)*8];
                    accd[nt] = __builtin_amdgcn_mfma_f32_16x16x32_bf16(a, b, accd[nt], 0, 0, 0);
                }
            }
            #pragma unroll
            for (int reg = 0; reg < 4; ++reg)
                #pragma unroll
                for (int nt = 0; nt < 4; ++nt) {
                    float vv = accd[nt][reg];
                    vv = vv > 0.f ? vv : 0.01f*vv;
                    sH[(m0 + q*4 + reg) * SHS + nt*16 + n15] = f2b(vv);
                }
        }

        // ---- SSC: d @ ssc_w -> sOut (LDS, [row][ch]) ----
        {
            f32x4 accs[2];
            #pragma unroll
            for (int nt = 0; nt < 2; ++nt) {
                const int col = nt*16 + n15;
                const float b = (col < NCLS) ? sscb[col] : 0.f;
                accs[nt] = (f32x4){b, b, b, b};
            }
            #pragma unroll
            for (int kc = 0; kc < 2; ++kc) {
                const bf16x8 a = *(const bf16x8*)&sH[(m0 + n15) * SHS + kc*32 + kq];
                #pragma unroll
                for (int nt = 0; nt < 2; ++nt) {
                    const bf16x8 b = *(const bf16x8*)&wt[SSCF + ((nt*2 + kc)*64 + lane)*8];
                    accs[nt] = __builtin_amdgcn_mfma_f32_16x16x32_bf16(a, b, accs[nt], 0, 0, 0);
                }
            }
            #pragma unroll
            for (int reg = 0; reg < 4; ++reg) {
                const int row = m0 + q*4 + reg;
                sOut[row*SOS + n15] = accs[0][reg];
                if (n15 < 4) sOut[row*SOS + 16 + n15] = accs[1][reg];
            }
        }

        __syncthreads();   // A: sOut done; stage(t+1) drained; sX/sH reads done

        // ---- coalesced SSC store: out[ch][p0+vox] <- sOut[vox][ch] ----
        #pragma unroll
        for (int jj = 0; jj < 5; ++jj) {
            const int i = tid + jj*256;       // i = ch*64 + vox
            out[(size_t)(i >> 6) * NVOX + p0 + (i & 63)] = sOut[(i & 63) * SOS + (i >> 6)];
        }

        // ---- pack next tile -> sX; publish next sRank ----
        if (t + 1 < TILES) {
            PACK();
            if (tid < TR) sRank[nb*TR + tid] = rkn;
        }
        __syncthreads();   // B: sX/sRank(t+1) ready; sOut free
    }
}

extern "C" void kernel_launch(void* const* d_in, const int* in_sizes, int n_in,
                              void* d_out, int out_size, void* d_ws, size_t ws_size,
                              hipStream_t stream) {
    const float* x3d  = (const float*)d_in[0];
    const float* w1   = (const float*)d_in[1];
    const float* b1   = (const float*)d_in[2];
    const float* lng  = (const float*)d_in[3];
    const float* lnb  = (const float*)d_in[4];
    const float* w2   = (const float*)d_in[5];
    const float* bb2  = (const float*)d_in[6];
    const float* sdbw = (const float*)d_in[7];
    const float* sdbb = (const float*)d_in[8];
    const float* sscw = (const float*)d_in[9];
    const float* sscb = (const float*)d_in[10];
    const float* auxw = (const float*)d_in[11];
    const float* auxb = (const float*)d_in[12];
    const int*   uidx = (const int*)d_in[13];
    const int*   midx = (const int*)d_in[14];
    float* out = (float*)d_out;
    u16*   wt  = (u16*)d_ws;
    const int* rank = (const int*)((const char*)d_ws + WS_WT*2);

    hipLaunchKernelGGL(prep_weights, dim3(128), dim3(256), 0, stream,
                       w1, w2, sdbw, sscw, auxw, uidx, midx, wt);
    hipLaunchKernelGGL(sgn_mfma, dim3(NBLK), dim3(256), 0, stream,
                       x3d, b1, lng, lnb, bb2, sdbb, sscb, auxb,
                       rank, wt, out);
}

// Round 8
// 249.992 us; speedup vs baseline: 1.4446x; 1.4446x over previous
//
#include <hip/hip_runtime.h>
#include <hip/hip_bf16.h>

// SGNHeadLSS — round 14: per-phase b-frag hoisting on the r9 base.
// r13 post-mortem: merged-phase + async-stage hit the (256,2)=128 VGPR
// cap and spilled (FETCH 392MB / WRITE 109MB) — 3rd spill strike; rule:
// no cross-phase register liveness. Clean results: r8 83.4 / r9 88 /
// r12 94, all pipes <22%. Arithmetic: ~30k cy wall per block vs ~5k
// issue; dominant wait = b-frag VMEM latency serialized at VGPR=52
// (~4 loads in flight -> 4-6 serialized groups x ~400cy per phase).
// Fix (phase-LOCAL, spill-safe):
//  - each GEMM phase loads b-frags into explicit bf[8] batches (fully
//    unrolled, static indexing) -> 8 loads in flight, 1-2 waits/phase.
//  - a-frags batched per phase (af[4]).
//  - pack: 8ch/thread -> 4x ds_write_b128 (was 16x conflicted b32).
// Structure/barriers/stores verbatim r9 (passed, absmax 0.024).

#define NVOX 262144
#define NU   65536
#define NM   196608
#define CIN  128
#define CHALF 64
#define NCLS 20
#define TR   64
#define NBLK (NVOX / TR)  // 4096

#define SXS 136   // sX row stride in u16 (272B, 16B-aligned)
#define SHS 72    // sH row stride in u16 (144B, 16B-aligned)
#define SOS 21    // sOut row stride in f32 (bank-conflict-free readback)

// ws layout (u16 units), fragment order: [nt][kc][lane]*8
#define W1F  0       // nt4 kc4  -> 8192
#define W2F  8192    // nt8 kc2  -> 8192
#define SDBF 16384   // nt4 kc4  -> 8192
#define SSCF 24576   // nt2 kc2  -> 2048
#define AUXF 26624   // nt2 kc4  -> 4096
#define WS_WT 30720  // 61440 bytes of weights; rank[NVOX] int32 follows

typedef unsigned short u16;
typedef short    bf16x8 __attribute__((ext_vector_type(8)));
typedef float    f32x4  __attribute__((ext_vector_type(4)));

__device__ __forceinline__ u16 f2b(float f) {
    __hip_bfloat16 h = __float2bfloat16(f);
    return *(u16*)&h;
}

// B-frag layout: lane=q*16+n15 holds B[k=kc*32+q*8+j][n=nt*16+n15], j=0..7
__global__ void prep_weights(const float* __restrict__ w1,  const float* __restrict__ w2,
                             const float* __restrict__ sdbw,const float* __restrict__ sscw,
                             const float* __restrict__ auxw,
                             const int* __restrict__ uidx,  const int* __restrict__ midx,
                             u16* __restrict__ ws) {
    int i = blockIdx.x * blockDim.x + threadIdx.x;
    const int stride = gridDim.x * blockDim.x;
    int* __restrict__ rank = (int*)(ws + WS_WT);
    for (int t = i; t < NU; t += stride) rank[uidx[t]] = t;
    for (int t = i; t < NM; t += stride) rank[midx[t]] = -1;
    for (; i < WS_WT; i += stride) {
        float v;
        if (i < W2F) {                      // w1^frag: N=64, K=128
            int t = i, j = t & 7, lane = (t >> 3) & 63, kc = (t >> 9) & 3, nt = t >> 11;
            int k = kc*32 + (lane >> 4)*8 + j, n = nt*16 + (lane & 15);
            v = w1[k*CHALF + n];
        } else if (i < SDBF) {              // w2^frag: N=128, K=64
            int t = i - W2F, j = t & 7, lane = (t >> 3) & 63, kc = (t >> 9) & 1, nt = t >> 10;
            int k = kc*32 + (lane >> 4)*8 + j, n = nt*16 + (lane & 15);
            v = w2[k*CIN + n];
        } else if (i < SSCF) {              // sdb^frag: N=64, K=128
            int t = i - SDBF, j = t & 7, lane = (t >> 3) & 63, kc = (t >> 9) & 3, nt = t >> 11;
            int k = kc*32 + (lane >> 4)*8 + j, n = nt*16 + (lane & 15);
            v = sdbw[k*CHALF + n];
        } else if (i < AUXF) {              // ssc^frag: N=32(pad), K=64
            int t = i - SSCF, j = t & 7, lane = (t >> 3) & 63, kc = (t >> 9) & 1, nt = t >> 10;
            int k = kc*32 + (lane >> 4)*8 + j, n = nt*16 + (lane & 15);
            v = (n < NCLS) ? sscw[k*NCLS + n] : 0.f;
        } else {                            // aux^frag: N=32(pad), K=128
            int t = i - AUXF, j = t & 7, lane = (t >> 3) & 63, kc = (t >> 9) & 3, nt = t >> 11;
            int k = kc*32 + (lane >> 4)*8 + j, n = nt*16 + (lane & 15);
            v = (n < NCLS) ? auxw[k*NCLS + n] : 0.f;
        }
        ws[i] = f2b(v);
    }
}

__global__ __launch_bounds__(256, 4)
void sgn_mfma(const float* __restrict__ x3d,
              const float* __restrict__ b1,   const float* __restrict__ lng,
              const float* __restrict__ lnb,  const float* __restrict__ bb2,
              const float* __restrict__ sdbb, const float* __restrict__ sscb,
              const float* __restrict__ auxb,
              const int* __restrict__ rank,   const u16* __restrict__ wt,
              float* __restrict__ out)
{
    __shared__ __align__(16) u16 sX[TR * SXS];      // feats / vox  [r][k]
    __shared__ __align__(16) u16 sH[TR * SHS];      // h / d        [r][k]
    __shared__ __align__(16) float sOut[TR * SOS];  // ssc logits   [r][ch]
    __shared__ int sRank[TR];

    const int tid = threadIdx.x;
    const int p0  = (int)blockIdx.x * TR;

    // ---- dense coalesced x3d load + pack: 8 channels x 4 vox per thread ----
    // 8x global f32x4 (coalesced: 16 lanes x 16B = 256B per ch-row), then
    // 4x ds_write_b128 (was 16x b32 with 8-way conflicts).
    {
        const int gch = (tid >> 4) * 8;   // channel octet
        const int vp  = (tid & 15) * 4;   // voxel quad
        f32x4 cv[8];
        #pragma unroll
        for (int r = 0; r < 8; ++r)
            cv[r] = *(const f32x4*)&x3d[(size_t)(gch + r) * NVOX + p0 + vp];
        #pragma unroll
        for (int j = 0; j < 4; ++j) {
            bf16x8 row;
            #pragma unroll
            for (int r = 0; r < 8; ++r) ((u16*)&row)[r] = f2b(cv[r][j]);
            *(bf16x8*)&sX[(vp + j) * SXS + gch] = row;
        }
    }
    if (tid < TR) sRank[tid] = rank[p0 + tid];
    __syncthreads();   // barrier 1: sX + sRank cross-wave

    const int m0   = (tid >> 6) * 16;  // wave's 16-row slice
    const int lane = tid & 63;
    const int q    = lane >> 4;
    const int n15  = lane & 15;
    const int kq   = q * 8;

    // ---- GEMM1: feats[64x128] @ w1 -> LN -> leaky -> sH ----
    {
        f32x4 acc[4];
        #pragma unroll
        for (int nt = 0; nt < 4; ++nt) {
            const float b = b1[nt*16 + n15];
            acc[nt] = (f32x4){b, b, b, b};
        }
        bf16x8 af[4];
        #pragma unroll
        for (int kc = 0; kc < 4; ++kc)
            af[kc] = *(const bf16x8*)&sX[(m0 + n15) * SXS + kc*32 + kq];
        #pragma unroll
        for (int h = 0; h < 2; ++h) {         // half-phase: kc = 2h, 2h+1
            bf16x8 bf[8];
            #pragma unroll
            for (int kk = 0; kk < 2; ++kk)
                #pragma unroll
                for (int nt = 0; nt < 4; ++nt)
                    bf[kk*4 + nt] = *(const bf16x8*)&wt[W1F + ((nt*4 + (2*h+kk))*64 + lane)*8];
            #pragma unroll
            for (int kk = 0; kk < 2; ++kk)
                #pragma unroll
                for (int nt = 0; nt < 4; ++nt)
                    acc[nt] = __builtin_amdgcn_mfma_f32_16x16x32_bf16(af[2*h+kk], bf[kk*4+nt], acc[nt], 0, 0, 0);
        }
        float gv[4], ev[4];
        #pragma unroll
        for (int nt = 0; nt < 4; ++nt) { gv[nt] = lng[nt*16 + n15]; ev[nt] = lnb[nt*16 + n15]; }
        #pragma unroll
        for (int reg = 0; reg < 4; ++reg) {
            float s1 = acc[0][reg] + acc[1][reg] + acc[2][reg] + acc[3][reg];
            float s2 = acc[0][reg]*acc[0][reg] + acc[1][reg]*acc[1][reg]
                     + acc[2][reg]*acc[2][reg] + acc[3][reg]*acc[3][reg];
            #pragma unroll
            for (int m = 1; m <= 8; m <<= 1) {
                s1 += __shfl_xor(s1, m, 64);
                s2 += __shfl_xor(s2, m, 64);
            }
            const float mu  = s1 * (1.f/64.f);
            const float var = s2 * (1.f/64.f) - mu*mu;
            const float rs  = rsqrtf(var + 1e-5f);
            #pragma unroll
            for (int nt = 0; nt < 4; ++nt) {
                float h = (acc[nt][reg] - mu) * rs * gv[nt] + ev[nt];
                h = h > 0.f ? h : 0.01f*h;
                sH[(m0 + q*4 + reg) * SHS + nt*16 + n15] = f2b(h);
            }
        }
    }

    // ---- GEMM2: h[64x64] @ w2 -> prior; overwrite MASKED rows of sX ----
    {
        f32x4 acc2[8];
        #pragma unroll
        for (int nt = 0; nt < 8; ++nt) {
            const float b = bb2[nt*16 + n15];
            acc2[nt] = (f32x4){b, b, b, b};
        }
        bf16x8 af[2];
        #pragma unroll
        for (int kc = 0; kc < 2; ++kc)
            af[kc] = *(const bf16x8*)&sH[(m0 + n15) * SHS + kc*32 + kq];
        #pragma unroll
        for (int kc = 0; kc < 2; ++kc) {      // half-phase: 8 b-frags of kc
            bf16x8 bf[8];
            #pragma unroll
            for (int nt = 0; nt < 8; ++nt)
                bf[nt] = *(const bf16x8*)&wt[W2F + ((nt*2 + kc)*64 + lane)*8];
            #pragma unroll
            for (int nt = 0; nt < 8; ++nt)
                acc2[nt] = __builtin_amdgcn_mfma_f32_16x16x32_bf16(af[kc], bf[nt], acc2[nt], 0, 0, 0);
        }
        #pragma unroll
        for (int reg = 0; reg < 4; ++reg) {
            const int row = m0 + q*4 + reg;
            if (sRank[row] < 0) {          // masked -> vox = prior
                #pragma unroll
                for (int nt = 0; nt < 8; ++nt)
                    sX[row * SXS + nt*16 + n15] = f2b(acc2[nt][reg]);
            }                              // unmasked -> vox = feats
        }
    }

    // ---- SDB: vox[64x128] @ sdb_w -> leaky -> sH (= d) ----
    {
        f32x4 accd[4];
        #pragma unroll
        for (int nt = 0; nt < 4; ++nt) {
            const float b = sdbb[nt*16 + n15];
            accd[nt] = (f32x4){b, b, b, b};
        }
        bf16x8 af[4];
        #pragma unroll
        for (int kc = 0; kc < 4; ++kc)
            af[kc] = *(const bf16x8*)&sX[(m0 + n15) * SXS + kc*32 + kq];
        #pragma unroll
        for (int h = 0; h < 2; ++h) {
            bf16x8 bf[8];
            #pragma unroll
            for (int kk = 0; kk < 2; ++kk)
                #pragma unroll
                for (int nt = 0; nt < 4; ++nt)
                    bf[kk*4 + nt] = *(const bf16x8*)&wt[SDBF + ((nt*4 + (2*h+kk))*64 + lane)*8];
            #pragma unroll
            for (int kk = 0; kk < 2; ++kk)
                #pragma unroll
                for (int nt = 0; nt < 4; ++nt)
                    accd[nt] = __builtin_amdgcn_mfma_f32_16x16x32_bf16(af[2*h+kk], bf[kk*4+nt], accd[nt], 0, 0, 0);
        }
        #pragma unroll
        for (int reg = 0; reg < 4; ++reg)
            #pragma unroll
            for (int nt = 0; nt < 4; ++nt) {
                float vv = accd[nt][reg];
                vv = vv > 0.f ? vv : 0.01f*vv;
                sH[(m0 + q*4 + reg) * SHS + nt*16 + n15] = f2b(vv);
            }
    }

    // ---- SSC: d[64x64] @ ssc_w[64x20] -> sOut (LDS, [row][ch]) ----
    {
        f32x4 accs[2];
        #pragma unroll
        for (int nt = 0; nt < 2; ++nt) {
            const int col = nt*16 + n15;
            const float b = (col < NCLS) ? sscb[col] : 0.f;
            accs[nt] = (f32x4){b, b, b, b};
        }
        bf16x8 af[2];
        #pragma unroll
        for (int kc = 0; kc < 2; ++kc)
            af[kc] = *(const bf16x8*)&sH[(m0 + n15) * SHS + kc*32 + kq];
        bf16x8 bf[4];
        #pragma unroll
        for (int kc = 0; kc < 2; ++kc)
            #pragma unroll
            for (int nt = 0; nt < 2; ++nt)
                bf[kc*2 + nt] = *(const bf16x8*)&wt[SSCF + ((nt*2 + kc)*64 + lane)*8];
        #pragma unroll
        for (int kc = 0; kc < 2; ++kc)
            #pragma unroll
            for (int nt = 0; nt < 2; ++nt)
                accs[nt] = __builtin_amdgcn_mfma_f32_16x16x32_bf16(af[kc], bf[kc*2+nt], accs[nt], 0, 0, 0);
        #pragma unroll
        for (int reg = 0; reg < 4; ++reg) {
            const int row = m0 + q*4 + reg;
            sOut[row*SOS + n15] = accs[0][reg];
            if (n15 < 4) sOut[row*SOS + 16 + n15] = accs[1][reg];
        }
    }

    // ---- AUX: feats @ aux_w (all rows; only unmasked rows stored) ----
    f32x4 acca[2];
    {
        #pragma unroll
        for (int nt = 0; nt < 2; ++nt) {
            const int col = nt*16 + n15;
            const float b = (col < NCLS) ? auxb[col] : 0.f;
            acca[nt] = (f32x4){b, b, b, b};
        }
        bf16x8 af[4];
        #pragma unroll
        for (int kc = 0; kc < 4; ++kc)
            af[kc] = *(const bf16x8*)&sX[(m0 + n15) * SXS + kc*32 + kq];
        bf16x8 bf[8];
        #pragma unroll
        for (int kc = 0; kc < 4; ++kc)
            #pragma unroll
            for (int nt = 0; nt < 2; ++nt)
                bf[kc*2 + nt] = *(const bf16x8*)&wt[AUXF + ((nt*4 + kc)*64 + lane)*8];
        #pragma unroll
        for (int kc = 0; kc < 4; ++kc)
            #pragma unroll
            for (int nt = 0; nt < 2; ++nt)
                acca[nt] = __builtin_amdgcn_mfma_f32_16x16x32_bf16(af[kc], bf[kc*2+nt], acca[nt], 0, 0, 0);
    }
    __syncthreads();   // barrier 2: sOut complete (cross-wave readback)

    // ---- coalesced SSC store: out[ch][p0+vox] <- sOut[vox][ch] ----
    #pragma unroll
    for (int jj = 0; jj < 5; ++jj) {
        const int i = tid + jj*256;       // 1280 floats: i = ch*64 + vox
        out[(size_t)(i >> 6) * NVOX + p0 + (i & 63)] = sOut[(i & 63) * SOS + (i >> 6)];
    }

    // ---- AUX store, predicated on unmasked; rank gives dense row ----
    {
        const size_t base = (size_t)NCLS * NVOX;
        #pragma unroll
        for (int reg = 0; reg < 4; ++reg) {
            const int row = m0 + q*4 + reg;
            const int rk  = sRank[row];
            if (rk >= 0) {
                out[base + (size_t)rk * NCLS + n15] = acca[0][reg];
                if (n15 < 4)
                    out[base + (size_t)rk * NCLS + 16 + n15] = acca[1][reg];
            }
        }
    }
}

extern "C" void kernel_launch(void* const* d_in, const int* in_sizes, int n_in,
                              void* d_out, int out_size, void* d_ws, size_t ws_size,
                              hipStream_t stream) {
    const float* x3d  = (const float*)d_in[0];
    const float* w1   = (const float*)d_in[1];
    const float* b1   = (const float*)d_in[2];
    const float* lng  = (const float*)d_in[3];
    const float* lnb  = (const float*)d_in[4];
    const float* w2   = (const float*)d_in[5];
    const float* bb2  = (const float*)d_in[6];
    const float* sdbw = (const float*)d_in[7];
    const float* sdbb = (const float*)d_in[8];
    const float* sscw = (const float*)d_in[9];
    const float* sscb = (const float*)d_in[10];
    const float* auxw = (const float*)d_in[11];
    const float* auxb = (const float*)d_in[12];
    const int*   uidx = (const int*)d_in[13];
    const int*   midx = (const int*)d_in[14];
    float* out = (float*)d_out;
    u16*   wt  = (u16*)d_ws;
    const int* rank = (const int*)((const char*)d_ws + WS_WT*2);

    hipLaunchKernelGGL(prep_weights, dim3(128), dim3(256), 0, stream,
                       w1, w2, sdbw, sscw, auxw, uidx, midx, wt);
    hipLaunchKernelGGL(sgn_mfma, dim3(NBLK), dim3(256), 0, stream,
                       x3d, b1, lng, lnb, bb2, sdbb, sscb, auxb,
                       rank, wt, out);
}

// Round 10
// 249.529 us; speedup vs baseline: 1.4472x; 1.0019x over previous
//
#include <hip/hip_runtime.h>
#include <hip/hip_bf16.h>

// SGNHeadLSS — round 16 (= r15 resubmitted; round 9 was an infra failure:
// "MI355X container failed twice" — kernel never ran, no counters).
// r14 post-mortem: 79.9us; VGPR stayed 52 (compiler re-serialized bf
// batches); pipes unchanged vs r8 despite +33% occupancy => more BLOCKS
// don't fill the per-wave stall chain (~35k cy wall vs ~5k issue).
// Lever: halve the per-wave chain AND double resident waves at fixed
// LDS. 8 waves/block on the same 64-row tile; wave pair shares rows,
// half=w&1 splits N-columns of every phase (30 MFMA + 30 b-frag loads
// per wave, half the VALU). LDS ~32KB unchanged -> cap = wave limit:
// 4 blocks x 8 waves = 32 waves/CU (100%). New: LN cross-half partial
// exchange via 1KB sLN + barrier; 6 barriers total (proven ~free, r8).
// Phase-local bf[4] batches; launch_bounds(512,8) cap 64 VGPR.

#define NVOX 262144
#define NU   65536
#define NM   196608
#define CIN  128
#define CHALF 64
#define NCLS 20
#define TR   64
#define NBLK (NVOX / TR)  // 4096

#define SXS 136   // sX row stride in u16 (272B)
#define SHS 68    // sH row stride in u16 (136B; 2-way-free on frag reads)
#define SOS 21    // sOut row stride in f32

// ws layout (u16 units), fragment order: [nt][kc][lane]*8
#define W1F  0       // nt4 kc4  -> 8192
#define W2F  8192    // nt8 kc2  -> 8192
#define SDBF 16384   // nt4 kc4  -> 8192
#define SSCF 24576   // nt2 kc2  -> 2048
#define AUXF 26624   // nt2 kc4  -> 4096
#define WS_WT 30720  // 61440 bytes of weights; rank[NVOX] int32 follows

typedef unsigned short u16;
typedef short    bf16x4 __attribute__((ext_vector_type(4)));
typedef short    bf16x8 __attribute__((ext_vector_type(8)));
typedef float    f32x4  __attribute__((ext_vector_type(4)));

__device__ __forceinline__ u16 f2b(float f) {
    __hip_bfloat16 h = __float2bfloat16(f);
    return *(u16*)&h;
}

// B-frag layout: lane=q*16+n15 holds B[k=kc*32+q*8+j][n=nt*16+n15], j=0..7
__global__ void prep_weights(const float* __restrict__ w1,  const float* __restrict__ w2,
                             const float* __restrict__ sdbw,const float* __restrict__ sscw,
                             const float* __restrict__ auxw,
                             const int* __restrict__ uidx,  const int* __restrict__ midx,
                             u16* __restrict__ ws) {
    int i = blockIdx.x * blockDim.x + threadIdx.x;
    const int stride = gridDim.x * blockDim.x;
    int* __restrict__ rank = (int*)(ws + WS_WT);
    for (int t = i; t < NU; t += stride) rank[uidx[t]] = t;
    for (int t = i; t < NM; t += stride) rank[midx[t]] = -1;
    for (; i < WS_WT; i += stride) {
        float v;
        if (i < W2F) {                      // w1^frag: N=64, K=128
            int t = i, j = t & 7, lane = (t >> 3) & 63, kc = (t >> 9) & 3, nt = t >> 11;
            int k = kc*32 + (lane >> 4)*8 + j, n = nt*16 + (lane & 15);
            v = w1[k*CHALF + n];
        } else if (i < SDBF) {              // w2^frag: N=128, K=64
            int t = i - W2F, j = t & 7, lane = (t >> 3) & 63, kc = (t >> 9) & 1, nt = t >> 10;
            int k = kc*32 + (lane >> 4)*8 + j, n = nt*16 + (lane & 15);
            v = w2[k*CIN + n];
        } else if (i < SSCF) {              // sdb^frag: N=64, K=128
            int t = i - SDBF, j = t & 7, lane = (t >> 3) & 63, kc = (t >> 9) & 3, nt = t >> 11;
            int k = kc*32 + (lane >> 4)*8 + j, n = nt*16 + (lane & 15);
            v = sdbw[k*CHALF + n];
        } else if (i < AUXF) {              // ssc^frag: N=32(pad), K=64
            int t = i - SSCF, j = t & 7, lane = (t >> 3) & 63, kc = (t >> 9) & 1, nt = t >> 10;
            int k = kc*32 + (lane >> 4)*8 + j, n = nt*16 + (lane & 15);
            v = (n < NCLS) ? sscw[k*NCLS + n] : 0.f;
        } else {                            // aux^frag: N=32(pad), K=128
            int t = i - AUXF, j = t & 7, lane = (t >> 3) & 63, kc = (t >> 9) & 3, nt = t >> 11;
            int k = kc*32 + (lane >> 4)*8 + j, n = nt*16 + (lane & 15);
            v = (n < NCLS) ? auxw[k*NCLS + n] : 0.f;
        }
        ws[i] = f2b(v);
    }
}

__global__ __launch_bounds__(512, 8)
void sgn_mfma(const float* __restrict__ x3d,
              const float* __restrict__ b1,   const float* __restrict__ lng,
              const float* __restrict__ lnb,  const float* __restrict__ bb2,
              const float* __restrict__ sdbb, const float* __restrict__ sscb,
              const float* __restrict__ auxb,
              const int* __restrict__ rank,   const u16* __restrict__ wt,
              float* __restrict__ out)
{
    __shared__ __align__(16) u16 sX[TR * SXS];      // feats / vox   17408B
    __shared__ __align__(16) u16 sH[TR * SHS];      // h / d          8704B
    __shared__ __align__(16) float sOut[TR * SOS];  // ssc logits     5376B
    __shared__ float sLN[TR][2][2];                 // LN partials    1024B
    __shared__ int sRank[TR];                       //                 256B

    const int tid = threadIdx.x;
    const int p0  = (int)blockIdx.x * TR;

    // ---- pack: 4 channels x 4 vox per thread (512 threads, 8192 elems) ----
    {
        const int gch = (tid >> 4) * 4;   // channel quad
        const int vp  = (tid & 15) * 4;   // voxel quad
        f32x4 cv[4];
        #pragma unroll
        for (int r = 0; r < 4; ++r)
            cv[r] = *(const f32x4*)&x3d[(size_t)(gch + r) * NVOX + p0 + vp];
        #pragma unroll
        for (int j = 0; j < 4; ++j) {
            bf16x4 row;
            #pragma unroll
            for (int r = 0; r < 4; ++r) ((u16*)&row)[r] = f2b(cv[r][j]);
            *(bf16x4*)&sX[(vp + j) * SXS + gch] = row;
        }
    }
    if (tid < TR) sRank[tid] = rank[p0 + tid];
    __syncthreads();                       // B1: sX + sRank

    const int w    = tid >> 6;             // wave 0..7
    const int half = w & 1;                // column half of the pair
    const int m0   = (w >> 1) * 16;        // shared 16-row slice
    const int lane = tid & 63;
    const int q    = lane >> 4;
    const int n15  = lane & 15;
    const int kq   = q * 8;

    // ---- GEMM1: feats @ w1 (this wave: nt = half*2 + {0,1}) ----
    {
        const int ntb = half * 2;
        f32x4 acc[2];
        #pragma unroll
        for (int i = 0; i < 2; ++i) {
            const float b = b1[(ntb + i)*16 + n15];
            acc[i] = (f32x4){b, b, b, b};
        }
        bf16x8 af[4];
        #pragma unroll
        for (int kc = 0; kc < 4; ++kc)
            af[kc] = *(const bf16x8*)&sX[(m0 + n15) * SXS + kc*32 + kq];
        #pragma unroll
        for (int h2 = 0; h2 < 2; ++h2) {
            bf16x8 bf[4];
            #pragma unroll
            for (int kk = 0; kk < 2; ++kk)
                #pragma unroll
                for (int i = 0; i < 2; ++i)
                    bf[kk*2 + i] = *(const bf16x8*)&wt[W1F + (((ntb+i)*4 + (2*h2+kk))*64 + lane)*8];
            #pragma unroll
            for (int kk = 0; kk < 2; ++kk)
                #pragma unroll
                for (int i = 0; i < 2; ++i)
                    acc[i] = __builtin_amdgcn_mfma_f32_16x16x32_bf16(af[2*h2+kk], bf[kk*2+i], acc[i], 0, 0, 0);
        }
        // partial LN sums over this half's 32 cols
        float s1v[4], s2v[4];
        #pragma unroll
        for (int reg = 0; reg < 4; ++reg) {
            float s1 = acc[0][reg] + acc[1][reg];
            float s2 = acc[0][reg]*acc[0][reg] + acc[1][reg]*acc[1][reg];
            #pragma unroll
            for (int m = 1; m <= 8; m <<= 1) {
                s1 += __shfl_xor(s1, m, 64);
                s2 += __shfl_xor(s2, m, 64);
            }
            s1v[reg] = s1; s2v[reg] = s2;
        }
        if (n15 == 0) {
            #pragma unroll
            for (int reg = 0; reg < 4; ++reg) {
                const int row = m0 + q*4 + reg;
                sLN[row][half][0] = s1v[reg];
                sLN[row][half][1] = s2v[reg];
            }
        }
        __syncthreads();                   // B2: LN partials exchanged
        float gv[2], ev[2];
        #pragma unroll
        for (int i = 0; i < 2; ++i) { gv[i] = lng[(ntb+i)*16 + n15]; ev[i] = lnb[(ntb+i)*16 + n15]; }
        #pragma unroll
        for (int reg = 0; reg < 4; ++reg) {
            const int row = m0 + q*4 + reg;
            const float s1 = s1v[reg] + sLN[row][half^1][0];
            const float s2 = s2v[reg] + sLN[row][half^1][1];
            const float mu  = s1 * (1.f/64.f);
            const float var = s2 * (1.f/64.f) - mu*mu;
            const float rs  = rsqrtf(var + 1e-5f);
            #pragma unroll
            for (int i = 0; i < 2; ++i) {
                float h = (acc[i][reg] - mu) * rs * gv[i] + ev[i];
                h = h > 0.f ? h : 0.01f*h;
                sH[row * SHS + (ntb+i)*16 + n15] = f2b(h);
            }
        }
    }
    __syncthreads();                       // B3: sH (h) complete

    // ---- GEMM2: h @ w2 -> prior (this wave: nt = half*4 + {0..3}) ----
    {
        const int ntb2 = half * 4;
        f32x4 acc2[4];
        #pragma unroll
        for (int i = 0; i < 4; ++i) {
            const float b = bb2[(ntb2 + i)*16 + n15];
            acc2[i] = (f32x4){b, b, b, b};
        }
        bf16x8 af2[2];
        #pragma unroll
        for (int kc = 0; kc < 2; ++kc)
            af2[kc] = *(const bf16x8*)&sH[(m0 + n15) * SHS + kc*32 + kq];
        #pragma unroll
        for (int kc = 0; kc < 2; ++kc) {
            bf16x8 bf[4];
            #pragma unroll
            for (int i = 0; i < 4; ++i)
                bf[i] = *(const bf16x8*)&wt[W2F + (((ntb2+i)*2 + kc)*64 + lane)*8];
            #pragma unroll
            for (int i = 0; i < 4; ++i)
                acc2[i] = __builtin_amdgcn_mfma_f32_16x16x32_bf16(af2[kc], bf[i], acc2[i], 0, 0, 0);
        }
        #pragma unroll
        for (int reg = 0; reg < 4; ++reg) {
            const int row = m0 + q*4 + reg;
            if (sRank[row] < 0) {          // masked -> vox = prior (this half's cols)
                #pragma unroll
                for (int i = 0; i < 4; ++i)
                    sX[row * SXS + (ntb2+i)*16 + n15] = f2b(acc2[i][reg]);
            }
        }
    }
    __syncthreads();                       // B4: sX select complete

    // ---- SDB: vox @ sdb_w -> leaky -> d (this wave: nt = half*2 + {0,1}) ----
    {
        const int ntb = half * 2;
        f32x4 accd[2];
        #pragma unroll
        for (int i = 0; i < 2; ++i) {
            const float b = sdbb[(ntb + i)*16 + n15];
            accd[i] = (f32x4){b, b, b, b};
        }
        bf16x8 af[4];
        #pragma unroll
        for (int kc = 0; kc < 4; ++kc)
            af[kc] = *(const bf16x8*)&sX[(m0 + n15) * SXS + kc*32 + kq];
        #pragma unroll
        for (int h2 = 0; h2 < 2; ++h2) {
            bf16x8 bf[4];
            #pragma unroll
            for (int kk = 0; kk < 2; ++kk)
                #pragma unroll
                for (int i = 0; i < 2; ++i)
                    bf[kk*2 + i] = *(const bf16x8*)&wt[SDBF + (((ntb+i)*4 + (2*h2+kk))*64 + lane)*8];
            #pragma unroll
            for (int kk = 0; kk < 2; ++kk)
                #pragma unroll
                for (int i = 0; i < 2; ++i)
                    accd[i] = __builtin_amdgcn_mfma_f32_16x16x32_bf16(af[2*h2+kk], bf[kk*2+i], accd[i], 0, 0, 0);
        }
        #pragma unroll
        for (int reg = 0; reg < 4; ++reg) {
            const int row = m0 + q*4 + reg;
            #pragma unroll
            for (int i = 0; i < 2; ++i) {
                float vv = accd[i][reg];
                vv = vv > 0.f ? vv : 0.01f*vv;
                sH[row * SHS + (ntb+i)*16 + n15] = f2b(vv);
            }
        }
    }
    __syncthreads();                       // B5: sH (d) complete

    // ---- SSC: d @ ssc_w (this wave: nt = half) -> sOut ----
    {
        f32x4 accs;
        {
            const int col = half*16 + n15;
            const float b = (col < NCLS) ? sscb[col] : 0.f;
            accs = (f32x4){b, b, b, b};
        }
        bf16x8 af2[2];
        #pragma unroll
        for (int kc = 0; kc < 2; ++kc)
            af2[kc] = *(const bf16x8*)&sH[(m0 + n15) * SHS + kc*32 + kq];
        bf16x8 bf[2];
        #pragma unroll
        for (int kc = 0; kc < 2; ++kc)
            bf[kc] = *(const bf16x8*)&wt[SSCF + ((half*2 + kc)*64 + lane)*8];
        #pragma unroll
        for (int kc = 0; kc < 2; ++kc)
            accs = __builtin_amdgcn_mfma_f32_16x16x32_bf16(af2[kc], bf[kc], accs, 0, 0, 0);
        #pragma unroll
        for (int reg = 0; reg < 4; ++reg) {
            const int row = m0 + q*4 + reg;
            if (half == 0)      sOut[row*SOS + n15] = accs[reg];
            else if (n15 < 4)   sOut[row*SOS + 16 + n15] = accs[reg];
        }
    }

    // ---- AUX: feats @ aux_w (this wave: nt = half); store unmasked ----
    {
        f32x4 acca;
        {
            const int col = half*16 + n15;
            const float b = (col < NCLS) ? auxb[col] : 0.f;
            acca = (f32x4){b, b, b, b};
        }
        bf16x8 af[4];
        #pragma unroll
        for (int kc = 0; kc < 4; ++kc)
            af[kc] = *(const bf16x8*)&sX[(m0 + n15) * SXS + kc*32 + kq];
        bf16x8 bf[4];
        #pragma unroll
        for (int kc = 0; kc < 4; ++kc)
            bf[kc] = *(const bf16x8*)&wt[AUXF + ((half*4 + kc)*64 + lane)*8];
        #pragma unroll
        for (int kc = 0; kc < 4; ++kc)
            acca = __builtin_amdgcn_mfma_f32_16x16x32_bf16(af[kc], bf[kc], acca, 0, 0, 0);
        const size_t abase = (size_t)NCLS * NVOX;
        #pragma unroll
        for (int reg = 0; reg < 4; ++reg) {
            const int rk = sRank[m0 + q*4 + reg];
            if (rk >= 0) {
                if (half == 0)      out[abase + (size_t)rk * NCLS + n15] = acca[reg];
                else if (n15 < 4)   out[abase + (size_t)rk * NCLS + 16 + n15] = acca[reg];
            }
        }
    }
    __syncthreads();                       // B6: sOut complete

    // ---- coalesced SSC store: out[ch][p0+vox] <- sOut[vox][ch] ----
    #pragma unroll
    for (int jj = 0; jj < 2; ++jj) {
        const int i = tid + jj*512;        // i = ch*64 + vox
        out[(size_t)(i >> 6) * NVOX + p0 + (i & 63)] = sOut[(i & 63) * SOS + (i >> 6)];
    }
    {
        const int i = tid + 1024;
        if (i < 1280)
            out[(size_t)(i >> 6) * NVOX + p0 + (i & 63)] = sOut[(i & 63) * SOS + (i >> 6)];
    }
}

extern "C" void kernel_launch(void* const* d_in, const int* in_sizes, int n_in,
                              void* d_out, int out_size, void* d_ws, size_t ws_size,
                              hipStream_t stream) {
    const float* x3d  = (const float*)d_in[0];
    const float* w1   = (const float*)d_in[1];
    const float* b1   = (const float*)d_in[2];
    const float* lng  = (const float*)d_in[3];
    const float* lnb  = (const float*)d_in[4];
    const float* w2   = (const float*)d_in[5];
    const float* bb2  = (const float*)d_in[6];
    const float* sdbw = (const float*)d_in[7];
    const float* sdbb = (const float*)d_in[8];
    const float* sscw = (const float*)d_in[9];
    const float* sscb = (const float*)d_in[10];
    const float* auxw = (const float*)d_in[11];
    const float* auxb = (const float*)d_in[12];
    const int*   uidx = (const int*)d_in[13];
    const int*   midx = (const int*)d_in[14];
    float* out = (float*)d_out;
    u16*   wt  = (u16*)d_ws;
    const int* rank = (const int*)((const char*)d_ws + WS_WT*2);

    hipLaunchKernelGGL(prep_weights, dim3(128), dim3(256), 0, stream,
                       w1, w2, sdbw, sscw, auxw, uidx, midx, wt);
    hipLaunchKernelGGL(sgn_mfma, dim3(NBLK), dim3(512), 0, stream,
                       x3d, b1, lng, lnb, bb2, sdbb, sscb, auxb,
                       rank, wt, out);
}